// Round 1
// baseline (3156.765 us; speedup 1.0000x reference)
//
#include <hip/hip_runtime.h>

static __device__ __forceinline__ float leaky(float v) { return v >= 0.f ? v : 0.01f * v; }

__global__ __launch_bounds__(256) void k_init_deg(float* deg, int n) {
    int i = blockIdx.x * 256 + threadIdx.x;
    if (i < n) deg[i] = 1.0f;   // self-loop contributes 1
}

__global__ __launch_bounds__(256) void k_count_deg(const int* __restrict__ dst, float* deg, int E) {
    int e = blockIdx.x * 256 + threadIdx.x;
    if (e < E) atomicAdd(&deg[dst[e]], 1.0f);
}

__global__ __launch_bounds__(256) void k_make_dinv(float* deg, int n) {
    int i = blockIdx.x * 256 + threadIdx.x;
    if (i < n) deg[i] = rsqrtf(deg[i]);   // deg >= 1 always (self loop)
}

// out[i,:] = x[i,:] * dinv[i]^2   (the self-loop term), one float4 per thread
__global__ __launch_bounds__(256) void k_agg_init(const float* __restrict__ x,
                                                  const float* __restrict__ dinv,
                                                  float* __restrict__ out, int n32) {
    int idx = blockIdx.x * 256 + threadIdx.x;
    if (idx >= n32) return;
    int node = idx >> 5;
    float di = dinv[node];
    float s = di * di;
    float4 v = ((const float4*)x)[idx];
    v.x *= s; v.y *= s; v.z *= s; v.w *= s;
    ((float4*)out)[idx] = v;
}

// out[dst,:] += x[src,:] * dinv[src]*dinv[dst]; 32 threads (float4 each) per edge
__global__ __launch_bounds__(256) void k_agg_scatter(const float* __restrict__ x,
                                                     const int* __restrict__ src,
                                                     const int* __restrict__ dst,
                                                     const float* __restrict__ dinv,
                                                     float* __restrict__ out, int E) {
    long long idx = (long long)blockIdx.x * 256 + threadIdx.x;
    if (idx >= (long long)E * 32) return;
    int e = (int)(idx >> 5), c = (int)(idx & 31);
    int s = src[e], d = dst[e];
    float nrm = dinv[s] * dinv[d];
    float4 v = *(const float4*)(x + (size_t)s * 128 + c * 4);
    float* o = out + (size_t)d * 128 + c * 4;
    atomicAdd(o + 0, v.x * nrm);
    atomicAdd(o + 1, v.y * nrm);
    atomicAdd(o + 2, v.z * nrm);
    atomicAdd(o + 3, v.w * nrm);
}

// h[i,f] = leaky(h[i,f] + bias[f]) over [n, 128]
__global__ __launch_bounds__(256) void k_bias_leaky(float* __restrict__ h,
                                                    const float* __restrict__ bias, int n32) {
    int idx = blockIdx.x * 256 + threadIdx.x;
    if (idx >= n32) return;
    int f4 = idx & 31;
    float4 v = ((float4*)h)[idx];
    float4 b = ((const float4*)bias)[f4];
    v.x = leaky(v.x + b.x); v.y = leaky(v.y + b.y);
    v.z = leaky(v.z + b.z); v.w = leaky(v.w + b.w);
    ((float4*)h)[idx] = v;
}

// C[M,N] = act(A[M,K] @ B + bias). B is [K,N] row-major if !TRANSB, else [N,K] row-major.
// 64x64 tile, 256 threads, 4x4 micro-tile, K-step 16. N,K multiples of 16/64; only M ragged.
template <bool TRANSB, bool ACT, bool BIAS>
__global__ __launch_bounds__(256) void k_gemm(const float* __restrict__ A,
                                              const float* __restrict__ B,
                                              const float* __restrict__ bias,
                                              float* __restrict__ C,
                                              int M, int N, int K) {
    __shared__ float As[16][64];
    __shared__ float Bs[16][64];
    int tid = threadIdx.x;
    int nbx = N >> 6;
    int bx = blockIdx.x % nbx;
    int by = blockIdx.x / nbx;
    int rowBase = by * 64, colBase = bx * 64;
    int tx = tid & 15, ty = tid >> 4;

    float acc[4][4] = {};

    int arow = tid >> 2, akq = tid & 3;   // A-tile: row 0..63, k-quad 0..3

    for (int k0 = 0; k0 < K; k0 += 16) {
        // load A tile (64 rows x 16 k), float4 along K
        float4 a4;
        int gr = rowBase + arow;
        if (gr < M) a4 = *(const float4*)(A + (size_t)gr * K + k0 + akq * 4);
        else a4 = make_float4(0.f, 0.f, 0.f, 0.f);
        As[akq * 4 + 0][arow] = a4.x;
        As[akq * 4 + 1][arow] = a4.y;
        As[akq * 4 + 2][arow] = a4.z;
        As[akq * 4 + 3][arow] = a4.w;

        if (TRANSB) {
            int bn = tid >> 2, bkq = tid & 3;
            float4 b4 = *(const float4*)(B + (size_t)(colBase + bn) * K + k0 + bkq * 4);
            Bs[bkq * 4 + 0][bn] = b4.x;
            Bs[bkq * 4 + 1][bn] = b4.y;
            Bs[bkq * 4 + 2][bn] = b4.z;
            Bs[bkq * 4 + 3][bn] = b4.w;
        } else {
            int bk = tid >> 4, bn4 = tid & 15;
            float4 b4 = *(const float4*)(B + (size_t)(k0 + bk) * N + colBase + bn4 * 4);
            *(float4*)&Bs[bk][bn4 * 4] = b4;
        }
        __syncthreads();

        #pragma unroll
        for (int k = 0; k < 16; ++k) {
            float4 av = *(const float4*)&As[k][ty * 4];
            float4 bv = *(const float4*)&Bs[k][tx * 4];
            acc[0][0] += av.x * bv.x; acc[0][1] += av.x * bv.y; acc[0][2] += av.x * bv.z; acc[0][3] += av.x * bv.w;
            acc[1][0] += av.y * bv.x; acc[1][1] += av.y * bv.y; acc[1][2] += av.y * bv.z; acc[1][3] += av.y * bv.w;
            acc[2][0] += av.z * bv.x; acc[2][1] += av.z * bv.y; acc[2][2] += av.z * bv.z; acc[2][3] += av.z * bv.w;
            acc[3][0] += av.w * bv.x; acc[3][1] += av.w * bv.y; acc[3][2] += av.w * bv.z; acc[3][3] += av.w * bv.w;
        }
        __syncthreads();
    }

    // epilogue
    #pragma unroll
    for (int i = 0; i < 4; ++i) {
        int r = rowBase + ty * 4 + i;
        if (r >= M) continue;
        float4 o = make_float4(acc[i][0], acc[i][1], acc[i][2], acc[i][3]);
        if (BIAS) {
            float4 b = *(const float4*)(bias + colBase + tx * 4);
            o.x += b.x; o.y += b.y; o.z += b.z; o.w += b.w;
        }
        if (ACT) { o.x = leaky(o.x); o.y = leaky(o.y); o.z = leaky(o.z); o.w = leaky(o.w); }
        *(float4*)(C + (size_t)r * N + colBase + tx * 4) = o;
    }
}

// out[i] = h[i,:256] . w[:256] + b; one wave per node
__global__ __launch_bounds__(256) void k_fc2(const float* __restrict__ h,
                                             const float* __restrict__ w,
                                             const float* __restrict__ b,
                                             float* __restrict__ out, int M) {
    int wave = (blockIdx.x * 256 + threadIdx.x) >> 6;
    int lane = threadIdx.x & 63;
    if (wave >= M) return;
    float4 v = *(const float4*)(h + (size_t)wave * 256 + lane * 4);
    float4 wv = *(const float4*)(w + lane * 4);
    float s = v.x * wv.x + v.y * wv.y + v.z * wv.z + v.w * wv.w;
    #pragma unroll
    for (int off = 32; off > 0; off >>= 1) s += __shfl_down(s, off);
    if (lane == 0) out[wave] = s + b[0];
}

extern "C" void kernel_launch(void* const* d_in, const int* in_sizes, int n_in,
                              void* d_out, int out_size, void* d_ws, size_t ws_size,
                              hipStream_t stream) {
    const float* x    = (const float*)d_in[0];
    const int*   ei   = (const int*)d_in[1];
    const float* W1   = (const float*)d_in[2];
    const float* b1   = (const float*)d_in[3];
    const float* W3   = (const float*)d_in[4];
    const float* b3   = (const float*)d_in[5];
    const float* fc1w = (const float*)d_in[6];
    const float* fc1b = (const float*)d_in[7];
    const float* fc2w = (const float*)d_in[8];
    const float* fc2b = (const float*)d_in[9];
    float* out = (float*)d_out;

    const int N = in_sizes[0] / 128;   // 50000
    const int E = in_sizes[1] / 2;     // 800000
    const int* src = ei;
    const int* dst = ei + E;

    char* ws = (char*)d_ws;
    size_t off = 0;
    float* dinv = (float*)(ws + off); off += ((size_t)N * 4 + 255) & ~255ull;
    float* bufA = (float*)(ws + off); off += (size_t)N * 128 * 4;   // agg1 then t2
    float* bufC = (float*)(ws + off); off += (size_t)N * 128 * 4;   // agg2 / h2
    float* big  = (float*)(ws + off); off += (size_t)N * 512 * 4;   // h1 then h3
    (void)ws_size; (void)n_in; (void)out_size;

    const int MB64 = (N + 63) / 64;    // 782
    dim3 blk(256);

    // degrees -> dinv
    k_init_deg<<<(N + 255) / 256, blk, 0, stream>>>(dinv, N);
    k_count_deg<<<(E + 255) / 256, blk, 0, stream>>>(dst, dinv, E);
    k_make_dinv<<<(N + 255) / 256, blk, 0, stream>>>(dinv, N);

    // agg1 = Agg(x)  [N,128]
    int n32 = N * 32;
    k_agg_init<<<(n32 + 255) / 256, blk, 0, stream>>>(x, dinv, bufA, n32);
    long long e32 = (long long)E * 32;
    k_agg_scatter<<<(int)((e32 + 255) / 256), blk, 0, stream>>>(x, src, dst, dinv, bufA, E);

    // h1 = leaky(agg1 @ W1 + b1)  [N,512]
    k_gemm<false, true, true><<<MB64 * (512 / 64), blk, 0, stream>>>(bufA, W1, b1, big, N, 512, 128);

    // t2 = h1 @ W3  [N,128]  (bias after aggregation)
    k_gemm<false, false, false><<<MB64 * (128 / 64), blk, 0, stream>>>(big, W3, nullptr, bufA, N, 128, 512);

    // agg2 = Agg(t2); h2 = leaky(agg2 + b3)  [N,128]
    k_agg_init<<<(n32 + 255) / 256, blk, 0, stream>>>(bufA, dinv, bufC, n32);
    k_agg_scatter<<<(int)((e32 + 255) / 256), blk, 0, stream>>>(bufA, src, dst, dinv, bufC, E);
    k_bias_leaky<<<(n32 + 255) / 256, blk, 0, stream>>>(bufC, b3, n32);

    // h3 = leaky(h2 @ fc1_w^T + fc1_b)  [N,256]
    k_gemm<true, true, true><<<MB64 * (256 / 64), blk, 0, stream>>>(bufC, fc1w, fc1b, big, N, 256, 128);

    // out = h3 @ fc2_w^T + fc2_b  [N]
    k_fc2<<<(N + 3) / 4, blk, 0, stream>>>(big, fc2w, fc2b, out, N);
}

// Round 2
// 584.922 us; speedup vs baseline: 5.3969x; 5.3969x over previous
//
#include <hip/hip_runtime.h>

static __device__ __forceinline__ float leaky(float v) { return v >= 0.f ? v : 0.01f * v; }

// ---------------- CSR build ----------------
__global__ __launch_bounds__(256) void k_deg(const int* __restrict__ dst, int* __restrict__ deg, int E) {
    int e = blockIdx.x * 256 + threadIdx.x;
    if (e < E) atomicAdd(&deg[dst[e]], 1);
}

__global__ __launch_bounds__(256) void k_scan1(const int* __restrict__ deg, int* __restrict__ part,
                                               int* __restrict__ bsum, int n) {
    __shared__ int s[256];
    int tx = threadIdx.x, i = blockIdx.x * 256 + tx;
    int v = (i < n) ? deg[i] : 0;
    s[tx] = v; __syncthreads();
    for (int off = 1; off < 256; off <<= 1) {
        int t = (tx >= off) ? s[tx - off] : 0;
        __syncthreads();
        s[tx] += t;
        __syncthreads();
    }
    if (i < n) part[i] = s[tx] - v;           // exclusive within block
    if (tx == 255) bsum[blockIdx.x] = s[255]; // block total
}

__global__ __launch_bounds__(256) void k_scan2(int* __restrict__ bsum, int nb) {
    __shared__ int s[256];
    int tx = threadIdx.x;
    int v = (tx < nb) ? bsum[tx] : 0;
    s[tx] = v; __syncthreads();
    for (int off = 1; off < 256; off <<= 1) {
        int t = (tx >= off) ? s[tx - off] : 0;
        __syncthreads();
        s[tx] += t;
        __syncthreads();
    }
    if (tx < nb) bsum[tx] = s[tx] - v;        // exclusive across blocks
}

__global__ __launch_bounds__(256) void k_scan3(const int* __restrict__ part, const int* __restrict__ bsum,
                                               int* __restrict__ rowptr, int n, int E) {
    int i = blockIdx.x * 256 + threadIdx.x;
    if (i < n) rowptr[i] = part[i] + bsum[i >> 8];
    else if (i == n) rowptr[n] = E;
}

__global__ __launch_bounds__(256) void k_fill(const int* __restrict__ src, const int* __restrict__ dst,
                                              const int* __restrict__ rowptr, int* __restrict__ cursor,
                                              int* __restrict__ csr, int E) {
    int e = blockIdx.x * 256 + threadIdx.x;
    if (e >= E) return;
    int d = dst[e];
    int pos = atomicAdd(&cursor[d], 1);
    csr[rowptr[d] + pos] = src[e];
}

__global__ __launch_bounds__(256) void k_dinv(const int* __restrict__ deg, float* __restrict__ dinv, int n) {
    int i = blockIdx.x * 256 + threadIdx.x;
    if (i < n) dinv[i] = rsqrtf((float)deg[i] + 1.0f);  // +1 = self loop
}

// ---------------- gather aggregation ----------------
// out[d,:] = dinv[d] * ( X[d,:]*dinv[d] + sum_{s in N(d)} X[s,:]*dinv[s] )
// one wave per node, float2 per lane; optional fused bias+leaky
template <bool BIASACT>
__global__ __launch_bounds__(256) void k_gather(const float* __restrict__ X,
                                                const int* __restrict__ rowptr,
                                                const int* __restrict__ csr,
                                                const float* __restrict__ dinv,
                                                const float* __restrict__ bias,
                                                float* __restrict__ out, int N) {
    int wid = (blockIdx.x * 256 + threadIdx.x) >> 6;
    if (wid >= N) return;
    int lane = threadIdx.x & 63, c = lane * 2;
    float di = dinv[wid];
    float2 self = *(const float2*)(X + (size_t)wid * 128 + c);
    float2 acc;
    acc.x = self.x * di;
    acc.y = self.y * di;
    int k = rowptr[wid], end = rowptr[wid + 1];
    for (; k + 4 <= end; k += 4) {
        int s0 = csr[k], s1 = csr[k + 1], s2 = csr[k + 2], s3 = csr[k + 3];
        float d0 = dinv[s0], d1 = dinv[s1], d2 = dinv[s2], d3 = dinv[s3];
        float2 v0 = *(const float2*)(X + (size_t)s0 * 128 + c);
        float2 v1 = *(const float2*)(X + (size_t)s1 * 128 + c);
        float2 v2 = *(const float2*)(X + (size_t)s2 * 128 + c);
        float2 v3 = *(const float2*)(X + (size_t)s3 * 128 + c);
        acc.x += v0.x * d0 + v1.x * d1 + v2.x * d2 + v3.x * d3;
        acc.y += v0.y * d0 + v1.y * d1 + v2.y * d2 + v3.y * d3;
    }
    for (; k < end; ++k) {
        int s0 = csr[k];
        float d0 = dinv[s0];
        float2 v0 = *(const float2*)(X + (size_t)s0 * 128 + c);
        acc.x += v0.x * d0;
        acc.y += v0.y * d0;
    }
    acc.x *= di;
    acc.y *= di;
    if (BIASACT) {
        acc.x = leaky(acc.x + bias[c]);
        acc.y = leaky(acc.y + bias[c + 1]);
    }
    *(float2*)(out + (size_t)wid * 128 + c) = acc;
}

// ---------------- GEMM ----------------
// C[M,N] = act(A[M,K] @ B + bias). B is [K,N] row-major if !TRANSB, else [N,K] row-major.
template <bool TRANSB, bool ACT, bool BIAS>
__global__ __launch_bounds__(256) void k_gemm(const float* __restrict__ A,
                                              const float* __restrict__ B,
                                              const float* __restrict__ bias,
                                              float* __restrict__ C,
                                              int M, int N, int K) {
    __shared__ float As[16][64];
    __shared__ float Bs[16][64];
    int tid = threadIdx.x;
    int nbx = N >> 6;
    int bx = blockIdx.x % nbx;
    int by = blockIdx.x / nbx;
    int rowBase = by * 64, colBase = bx * 64;
    int tx = tid & 15, ty = tid >> 4;

    float acc[4][4] = {};

    int arow = tid >> 2, akq = tid & 3;

    for (int k0 = 0; k0 < K; k0 += 16) {
        float4 a4;
        int gr = rowBase + arow;
        if (gr < M) a4 = *(const float4*)(A + (size_t)gr * K + k0 + akq * 4);
        else a4 = make_float4(0.f, 0.f, 0.f, 0.f);
        As[akq * 4 + 0][arow] = a4.x;
        As[akq * 4 + 1][arow] = a4.y;
        As[akq * 4 + 2][arow] = a4.z;
        As[akq * 4 + 3][arow] = a4.w;

        if (TRANSB) {
            int bn = tid >> 2, bkq = tid & 3;
            float4 b4 = *(const float4*)(B + (size_t)(colBase + bn) * K + k0 + bkq * 4);
            Bs[bkq * 4 + 0][bn] = b4.x;
            Bs[bkq * 4 + 1][bn] = b4.y;
            Bs[bkq * 4 + 2][bn] = b4.z;
            Bs[bkq * 4 + 3][bn] = b4.w;
        } else {
            int bk = tid >> 4, bn4 = tid & 15;
            float4 b4 = *(const float4*)(B + (size_t)(k0 + bk) * N + colBase + bn4 * 4);
            *(float4*)&Bs[bk][bn4 * 4] = b4;
        }
        __syncthreads();

        #pragma unroll
        for (int k = 0; k < 16; ++k) {
            float4 av = *(const float4*)&As[k][ty * 4];
            float4 bv = *(const float4*)&Bs[k][tx * 4];
            acc[0][0] += av.x * bv.x; acc[0][1] += av.x * bv.y; acc[0][2] += av.x * bv.z; acc[0][3] += av.x * bv.w;
            acc[1][0] += av.y * bv.x; acc[1][1] += av.y * bv.y; acc[1][2] += av.y * bv.z; acc[1][3] += av.y * bv.w;
            acc[2][0] += av.z * bv.x; acc[2][1] += av.z * bv.y; acc[2][2] += av.z * bv.z; acc[2][3] += av.z * bv.w;
            acc[3][0] += av.w * bv.x; acc[3][1] += av.w * bv.y; acc[3][2] += av.w * bv.z; acc[3][3] += av.w * bv.w;
        }
        __syncthreads();
    }

    #pragma unroll
    for (int i = 0; i < 4; ++i) {
        int r = rowBase + ty * 4 + i;
        if (r >= M) continue;
        float4 o = make_float4(acc[i][0], acc[i][1], acc[i][2], acc[i][3]);
        if (BIAS) {
            float4 b = *(const float4*)(bias + colBase + tx * 4);
            o.x += b.x; o.y += b.y; o.z += b.z; o.w += b.w;
        }
        if (ACT) { o.x = leaky(o.x); o.y = leaky(o.y); o.z = leaky(o.z); o.w = leaky(o.w); }
        *(float4*)(C + (size_t)r * N + colBase + tx * 4) = o;
    }
}

// out[i] = h[i,:256] . w[:256] + b; one wave per node
__global__ __launch_bounds__(256) void k_fc2(const float* __restrict__ h,
                                             const float* __restrict__ w,
                                             const float* __restrict__ b,
                                             float* __restrict__ out, int M) {
    int wave = (blockIdx.x * 256 + threadIdx.x) >> 6;
    int lane = threadIdx.x & 63;
    if (wave >= M) return;
    float4 v = *(const float4*)(h + (size_t)wave * 256 + lane * 4);
    float4 wv = *(const float4*)(w + lane * 4);
    float s = v.x * wv.x + v.y * wv.y + v.z * wv.z + v.w * wv.w;
    #pragma unroll
    for (int off = 32; off > 0; off >>= 1) s += __shfl_down(s, off);
    if (lane == 0) out[wave] = s + b[0];
}

extern "C" void kernel_launch(void* const* d_in, const int* in_sizes, int n_in,
                              void* d_out, int out_size, void* d_ws, size_t ws_size,
                              hipStream_t stream) {
    const float* x    = (const float*)d_in[0];
    const int*   ei   = (const int*)d_in[1];
    const float* W1   = (const float*)d_in[2];
    const float* b1   = (const float*)d_in[3];
    const float* W3   = (const float*)d_in[4];
    const float* b3   = (const float*)d_in[5];
    const float* fc1w = (const float*)d_in[6];
    const float* fc1b = (const float*)d_in[7];
    const float* fc2w = (const float*)d_in[8];
    const float* fc2b = (const float*)d_in[9];
    float* out = (float*)d_out;

    const int N = in_sizes[0] / 128;   // 50000
    const int E = in_sizes[1] / 2;     // 800000
    const int* src = ei;
    const int* dst = ei + E;

    char* ws = (char*)d_ws;
    size_t off = 0;
    auto alloc = [&](size_t bytes) { void* p = ws + off; off += (bytes + 255) & ~255ull; return p; };
    int*   deg    = (int*)alloc((size_t)N * 4);
    int*   part   = (int*)alloc((size_t)N * 4);
    int*   bsum   = (int*)alloc(256 * 4);
    int*   cursor = (int*)alloc((size_t)N * 4);
    int*   rowptr = (int*)alloc((size_t)(N + 1) * 4);
    int*   csr    = (int*)alloc((size_t)E * 4);
    float* dinv   = (float*)alloc((size_t)N * 4);
    float* bufA   = (float*)alloc((size_t)N * 128 * 4);
    float* bufC   = (float*)alloc((size_t)N * 128 * 4);
    float* big    = (float*)alloc((size_t)N * 512 * 4);
    (void)ws_size; (void)n_in; (void)out_size;

    const int MB64 = (N + 63) / 64;
    const int nb = (N + 255) / 256;    // 196 scan blocks (<=256)
    dim3 blk(256);

    // CSR build
    hipMemsetAsync(deg, 0, (size_t)N * 4, stream);
    k_deg<<<(E + 255) / 256, blk, 0, stream>>>(dst, deg, E);
    k_scan1<<<nb, blk, 0, stream>>>(deg, part, bsum, N);
    k_scan2<<<1, blk, 0, stream>>>(bsum, nb);
    k_scan3<<<(N + 256) / 256, blk, 0, stream>>>(part, bsum, rowptr, N, E);
    k_dinv<<<(N + 255) / 256, blk, 0, stream>>>(deg, dinv, N);
    hipMemsetAsync(cursor, 0, (size_t)N * 4, stream);
    k_fill<<<(E + 255) / 256, blk, 0, stream>>>(src, dst, rowptr, cursor, csr, E);

    // agg1 = Agg(x)  [N,128]
    k_gather<false><<<(N * 64 + 255) / 256, blk, 0, stream>>>(x, rowptr, csr, dinv, nullptr, bufA, N);

    // h1 = leaky(agg1 @ W1 + b1)  [N,512]
    k_gemm<false, true, true><<<MB64 * (512 / 64), blk, 0, stream>>>(bufA, W1, b1, big, N, 512, 128);

    // t2 = h1 @ W3  [N,128]
    k_gemm<false, false, false><<<MB64 * (128 / 64), blk, 0, stream>>>(big, W3, nullptr, bufA, N, 128, 512);

    // h2 = leaky(Agg(t2) + b3)  [N,128]
    k_gather<true><<<(N * 64 + 255) / 256, blk, 0, stream>>>(bufA, rowptr, csr, dinv, b3, bufC, N);

    // h3 = leaky(h2 @ fc1_w^T + fc1_b)  [N,256]
    k_gemm<true, true, true><<<MB64 * (256 / 64), blk, 0, stream>>>(bufC, fc1w, fc1b, big, N, 256, 128);

    // out = h3 @ fc2_w^T + fc2_b  [N]
    k_fc2<<<(N + 3) / 4, blk, 0, stream>>>(big, fc2w, fc2b, out, N);
}

// Round 3
// 405.188 us; speedup vs baseline: 7.7909x; 1.4436x over previous
//
#include <hip/hip_runtime.h>

typedef __attribute__((ext_vector_type(8))) short bf16x8;
typedef __attribute__((ext_vector_type(4))) float f32x4;

static __device__ __forceinline__ float leaky(float v) { return v >= 0.f ? v : 0.01f * v; }

// pack fp32 -> (bf16 hi in bits[15:0], bf16 lo in bits[31:16]), both RNE
static __device__ __forceinline__ unsigned int packsplit(float v) {
    unsigned int u = __float_as_uint(v);
    unsigned int hi = (u + 0x7FFFu + ((u >> 16) & 1u)) >> 16;
    float hf = __uint_as_float(hi << 16);
    float lof = v - hf;
    unsigned int ul = __float_as_uint(lof);
    unsigned int lo = (ul + 0x7FFFu + ((ul >> 16) & 1u)) >> 16;
    return (hi & 0xFFFFu) | (lo << 16);
}

// ---------------- CSR build ----------------
__global__ __launch_bounds__(256) void k_deg(const int* __restrict__ dst, int* __restrict__ deg, int E) {
    int e = blockIdx.x * 256 + threadIdx.x;
    if (e < E) atomicAdd(&deg[dst[e]], 1);
}

__global__ __launch_bounds__(256) void k_scan1(const int* __restrict__ deg, int* __restrict__ part,
                                               int* __restrict__ bsum, int n) {
    __shared__ int s[256];
    int tx = threadIdx.x, i = blockIdx.x * 256 + tx;
    int v = (i < n) ? deg[i] : 0;
    s[tx] = v; __syncthreads();
    for (int off = 1; off < 256; off <<= 1) {
        int t = (tx >= off) ? s[tx - off] : 0;
        __syncthreads();
        s[tx] += t;
        __syncthreads();
    }
    if (i < n) part[i] = s[tx] - v;
    if (tx == 255) bsum[blockIdx.x] = s[255];
}

__global__ __launch_bounds__(256) void k_scan2(int* __restrict__ bsum, int nb) {
    __shared__ int s[256];
    int tx = threadIdx.x;
    int v = (tx < nb) ? bsum[tx] : 0;
    s[tx] = v; __syncthreads();
    for (int off = 1; off < 256; off <<= 1) {
        int t = (tx >= off) ? s[tx - off] : 0;
        __syncthreads();
        s[tx] += t;
        __syncthreads();
    }
    if (tx < nb) bsum[tx] = s[tx] - v;
}

__global__ __launch_bounds__(256) void k_scan3(const int* __restrict__ part, const int* __restrict__ bsum,
                                               int* __restrict__ rowptr, int n, int E) {
    int i = blockIdx.x * 256 + threadIdx.x;
    if (i < n) rowptr[i] = part[i] + bsum[i >> 8];
    else if (i == n) rowptr[n] = E;
}

__global__ __launch_bounds__(256) void k_fill(const int* __restrict__ src, const int* __restrict__ dst,
                                              const int* __restrict__ rowptr, int* __restrict__ cursor,
                                              int* __restrict__ csr, int E) {
    int e = blockIdx.x * 256 + threadIdx.x;
    if (e >= E) return;
    int d = dst[e];
    int pos = atomicAdd(&cursor[d], 1);
    csr[rowptr[d] + pos] = src[e];
}

__global__ __launch_bounds__(256) void k_dinv(const int* __restrict__ deg, float* __restrict__ dinv, int n) {
    int i = blockIdx.x * 256 + threadIdx.x;
    if (i < n) dinv[i] = rsqrtf((float)deg[i] + 1.0f);
}

// ---------------- weight prep ----------------
// W [K][N] fp32 row-major -> out [N][K] packed u32
__global__ __launch_bounds__(256) void k_prepT(const float* __restrict__ W, unsigned int* __restrict__ out,
                                               int K, int N) {
    int idx = blockIdx.x * 256 + threadIdx.x;
    if (idx >= K * N) return;
    int k = idx / N, n = idx - k * N;
    out[(size_t)n * K + k] = packsplit(W[idx]);
}
// W already [N][K] -> packed elementwise
__global__ __launch_bounds__(256) void k_prep(const float* __restrict__ W, unsigned int* __restrict__ out, int sz) {
    int idx = blockIdx.x * 256 + threadIdx.x;
    if (idx < sz) out[idx] = packsplit(W[idx]);
}

__global__ __launch_bounds__(256) void k_outinit(float* __restrict__ out, const float* __restrict__ b, int n) {
    int i = blockIdx.x * 256 + threadIdx.x;
    if (i < n) out[i] = b[0];
}

// ---------------- gather aggregation (writes packed hi/lo) ----------------
template <bool BIASACT>
__global__ __launch_bounds__(256) void k_gather(const float* __restrict__ X,
                                                const int* __restrict__ rowptr,
                                                const int* __restrict__ csr,
                                                const float* __restrict__ dinv,
                                                const float* __restrict__ bias,
                                                unsigned int* __restrict__ outp, int N) {
    int wid = (blockIdx.x * 256 + threadIdx.x) >> 6;
    if (wid >= N) return;
    int lane = threadIdx.x & 63, c = lane * 2;
    float di = dinv[wid];
    float2 self = *(const float2*)(X + (size_t)wid * 128 + c);
    float2 acc;
    acc.x = self.x * di;
    acc.y = self.y * di;
    int k = rowptr[wid], end = rowptr[wid + 1];
    for (; k + 4 <= end; k += 4) {
        int s0 = csr[k], s1 = csr[k + 1], s2 = csr[k + 2], s3 = csr[k + 3];
        float d0 = dinv[s0], d1 = dinv[s1], d2 = dinv[s2], d3 = dinv[s3];
        float2 v0 = *(const float2*)(X + (size_t)s0 * 128 + c);
        float2 v1 = *(const float2*)(X + (size_t)s1 * 128 + c);
        float2 v2 = *(const float2*)(X + (size_t)s2 * 128 + c);
        float2 v3 = *(const float2*)(X + (size_t)s3 * 128 + c);
        acc.x += v0.x * d0 + v1.x * d1 + v2.x * d2 + v3.x * d3;
        acc.y += v0.y * d0 + v1.y * d1 + v2.y * d2 + v3.y * d3;
    }
    for (; k < end; ++k) {
        int s0 = csr[k];
        float d0 = dinv[s0];
        float2 v0 = *(const float2*)(X + (size_t)s0 * 128 + c);
        acc.x += v0.x * d0;
        acc.y += v0.y * d0;
    }
    acc.x *= di;
    acc.y *= di;
    if (BIASACT) {
        acc.x = leaky(acc.x + bias[c]);
        acc.y = leaky(acc.y + bias[c + 1]);
    }
    uint2 p;
    p.x = packsplit(acc.x);
    p.y = packsplit(acc.y);
    *(uint2*)(outp + (size_t)wid * 128 + c) = p;
}

// ---------------- MFMA GEMM (bf16 hi/lo x3) ----------------
// A: [M][K] packed u32; B: [Ntot][K] packed u32.
// MODE 0: C = A@B fp32 out [M][Ntot]
// MODE 1: C = packsplit(leaky(A@B + bias)) u32 out [M][Ntot]
// MODE 2: atomicAdd(out[row], sum_col leaky(A@B + bias)[col] * w2[col])
template <int MODE>
__global__ __launch_bounds__(256, 2) void k_mgemm(const unsigned int* __restrict__ Ap,
                                                  const unsigned int* __restrict__ Bp,
                                                  const float* __restrict__ bias,
                                                  const float* __restrict__ w2,
                                                  void* __restrict__ Cout,
                                                  int M, int Ntot, int K) {
    __shared__ __align__(16) unsigned short smem[16384]; // Ahi/Alo/Bhi/Blo, each [128][32] bf16
    unsigned short* Ahi = smem;
    unsigned short* Alo = smem + 4096;
    unsigned short* Bhi = smem + 8192;
    unsigned short* Blo = smem + 12288;

    const int tid = threadIdx.x, lane = tid & 63, wid = tid >> 6;
    const int wr = wid >> 1, wc = wid & 1;
    const int nbx = Ntot >> 7;
    const int bx = blockIdx.x % nbx, by = blockIdx.x / nbx;
    const int m0 = by * 128, n0 = bx * 128;
    const int rl = lane >> 3, cl = lane & 7;

    f32x4 acc[4][4] = {};
    uint4 rA[4], rB[4];

    auto issue = [&](int k0) {
        #pragma unroll
        for (int j = 0; j < 4; ++j) {
            int r = wid * 32 + j * 8 + rl;
            int ga = m0 + r; ga = (ga < M) ? ga : (M - 1);
            rA[j] = *(const uint4*)(Ap + (size_t)ga * K + k0 + cl * 4);
            rB[j] = *(const uint4*)(Bp + (size_t)(n0 + r) * K + k0 + cl * 4);
        }
    };
    auto commit = [&]() {
        #pragma unroll
        for (int j = 0; j < 4; ++j) {
            int r = wid * 32 + j * 8 + rl;
            int off = r * 32 + cl * 4;
            uint4 v = rA[j];
            uint2 h, l;
            h.x = (v.x & 0xFFFFu) | (v.y << 16);
            h.y = (v.z & 0xFFFFu) | (v.w << 16);
            l.x = (v.x >> 16) | (v.y & 0xFFFF0000u);
            l.y = (v.z >> 16) | (v.w & 0xFFFF0000u);
            *(uint2*)(Ahi + off) = h;
            *(uint2*)(Alo + off) = l;
            v = rB[j];
            h.x = (v.x & 0xFFFFu) | (v.y << 16);
            h.y = (v.z & 0xFFFFu) | (v.w << 16);
            l.x = (v.x >> 16) | (v.y & 0xFFFF0000u);
            l.y = (v.z >> 16) | (v.w & 0xFFFF0000u);
            *(uint2*)(Bhi + off) = h;
            *(uint2*)(Blo + off) = l;
        }
    };
    auto rdfrag = [&](const unsigned short* base, int rbase) -> bf16x8 {
        int row = rbase + (lane & 15);
        return *(const bf16x8*)(base + row * 32 + (lane >> 4) * 8);
    };

    const int nsteps = K >> 5;
    issue(0);
    commit();
    __syncthreads();
    for (int t = 0; t < nsteps; ++t) {
        if (t + 1 < nsteps) issue((t + 1) << 5);
        bf16x8 ah[4], al[4], bh[4], bl[4];
        #pragma unroll
        for (int i = 0; i < 4; ++i) {
            ah[i] = rdfrag(Ahi, wr * 64 + i * 16);
            al[i] = rdfrag(Alo, wr * 64 + i * 16);
            bh[i] = rdfrag(Bhi, wc * 64 + i * 16);
            bl[i] = rdfrag(Blo, wc * 64 + i * 16);
        }
        #pragma unroll
        for (int i = 0; i < 4; ++i) {
            #pragma unroll
            for (int n = 0; n < 4; ++n) {
                acc[i][n] = __builtin_amdgcn_mfma_f32_16x16x32_bf16(ah[i], bh[n], acc[i][n], 0, 0, 0);
                acc[i][n] = __builtin_amdgcn_mfma_f32_16x16x32_bf16(al[i], bh[n], acc[i][n], 0, 0, 0);
                acc[i][n] = __builtin_amdgcn_mfma_f32_16x16x32_bf16(ah[i], bl[n], acc[i][n], 0, 0, 0);
            }
        }
        __syncthreads();
        if (t + 1 < nsteps) { commit(); __syncthreads(); }
    }

    // epilogue
    if (MODE == 0) {
        float* C = (float*)Cout;
        #pragma unroll
        for (int i = 0; i < 4; ++i) {
            #pragma unroll
            for (int j = 0; j < 4; ++j) {
                int row = m0 + wr * 64 + i * 16 + (lane >> 4) * 4 + j;
                if (row < M) {
                    #pragma unroll
                    for (int n = 0; n < 4; ++n) {
                        int col = n0 + wc * 64 + n * 16 + (lane & 15);
                        C[(size_t)row * Ntot + col] = acc[i][n][j];
                    }
                }
            }
        }
    } else if (MODE == 1) {
        unsigned int* C = (unsigned int*)Cout;
        #pragma unroll
        for (int i = 0; i < 4; ++i) {
            #pragma unroll
            for (int j = 0; j < 4; ++j) {
                int row = m0 + wr * 64 + i * 16 + (lane >> 4) * 4 + j;
                if (row < M) {
                    #pragma unroll
                    for (int n = 0; n < 4; ++n) {
                        int col = n0 + wc * 64 + n * 16 + (lane & 15);
                        float v = leaky(acc[i][n][j] + bias[col]);
                        C[(size_t)row * Ntot + col] = packsplit(v);
                    }
                }
            }
        }
    } else {
        float* C = (float*)Cout;
        #pragma unroll
        for (int i = 0; i < 4; ++i) {
            #pragma unroll
            for (int j = 0; j < 4; ++j) {
                int row = m0 + wr * 64 + i * 16 + (lane >> 4) * 4 + j;
                float s = 0.f;
                #pragma unroll
                for (int n = 0; n < 4; ++n) {
                    int col = n0 + wc * 64 + n * 16 + (lane & 15);
                    float v = leaky(acc[i][n][j] + bias[col]);
                    s += v * w2[col];
                }
                s += __shfl_xor(s, 8);
                s += __shfl_xor(s, 4);
                s += __shfl_xor(s, 2);
                s += __shfl_xor(s, 1);
                if ((lane & 15) == 0 && row < M) atomicAdd(&C[row], s);
            }
        }
    }
}

extern "C" void kernel_launch(void* const* d_in, const int* in_sizes, int n_in,
                              void* d_out, int out_size, void* d_ws, size_t ws_size,
                              hipStream_t stream) {
    const float* x    = (const float*)d_in[0];
    const int*   ei   = (const int*)d_in[1];
    const float* W1   = (const float*)d_in[2];
    const float* b1   = (const float*)d_in[3];
    const float* W3   = (const float*)d_in[4];
    const float* b3   = (const float*)d_in[5];
    const float* fc1w = (const float*)d_in[6];
    const float* fc1b = (const float*)d_in[7];
    const float* fc2w = (const float*)d_in[8];
    const float* fc2b = (const float*)d_in[9];
    float* out = (float*)d_out;

    const int N = in_sizes[0] / 128;   // 50000
    const int E = in_sizes[1] / 2;     // 800000
    const int* src = ei;
    const int* dst = ei + E;

    char* ws = (char*)d_ws;
    size_t off = 0;
    auto alloc = [&](size_t bytes) { void* p = ws + off; off += (bytes + 255) & ~255ull; return p; };
    int*   deg    = (int*)alloc((size_t)N * 4);
    int*   part   = (int*)alloc((size_t)N * 4);
    int*   bsum   = (int*)alloc(256 * 4);
    int*   cursor = (int*)alloc((size_t)N * 4);
    int*   rowptr = (int*)alloc((size_t)(N + 1) * 4);
    int*   csr    = (int*)alloc((size_t)E * 4);
    float* dinv   = (float*)alloc((size_t)N * 4);
    unsigned int* A1p  = (unsigned int*)alloc((size_t)N * 128 * 4);
    unsigned int* H1p  = (unsigned int*)alloc((size_t)N * 512 * 4);
    float*        t2   = (float*)alloc((size_t)N * 128 * 4);
    unsigned int* A3p  = (unsigned int*)alloc((size_t)N * 128 * 4);
    unsigned int* W1T  = (unsigned int*)alloc((size_t)512 * 128 * 4);
    unsigned int* W3T  = (unsigned int*)alloc((size_t)128 * 512 * 4);
    unsigned int* F1p  = (unsigned int*)alloc((size_t)256 * 128 * 4);
    (void)ws_size; (void)n_in; (void)out_size;

    const int MB128 = (N + 127) / 128;  // 391
    const int nb = (N + 255) / 256;
    dim3 blk(256);

    // CSR build + dinv
    hipMemsetAsync(deg, 0, (size_t)N * 4, stream);
    k_deg<<<(E + 255) / 256, blk, 0, stream>>>(dst, deg, E);
    k_scan1<<<nb, blk, 0, stream>>>(deg, part, bsum, N);
    k_scan2<<<1, blk, 0, stream>>>(bsum, nb);
    k_scan3<<<(N + 256) / 256, blk, 0, stream>>>(part, bsum, rowptr, N, E);
    k_dinv<<<(N + 255) / 256, blk, 0, stream>>>(deg, dinv, N);
    hipMemsetAsync(cursor, 0, (size_t)N * 4, stream);
    k_fill<<<(E + 255) / 256, blk, 0, stream>>>(src, dst, rowptr, cursor, csr, E);

    // weight prep (packed hi/lo, [N][K] layouts)
    k_prepT<<<(128 * 512 + 255) / 256, blk, 0, stream>>>(W1, W1T, 128, 512);
    k_prepT<<<(512 * 128 + 255) / 256, blk, 0, stream>>>(W3, W3T, 512, 128);
    k_prep<<<(256 * 128 + 255) / 256, blk, 0, stream>>>(fc1w, F1p, 256 * 128);
    k_outinit<<<(N + 255) / 256, blk, 0, stream>>>(out, fc2b, N);

    // agg1 = Agg(x) -> packed [N,128]
    k_gather<false><<<(N * 64 + 255) / 256, blk, 0, stream>>>(x, rowptr, csr, dinv, nullptr, A1p, N);

    // h1 = leaky(agg1 @ W1 + b1) -> packed [N,512]
    k_mgemm<1><<<MB128 * 4, blk, 0, stream>>>(A1p, W1T, b1, nullptr, H1p, N, 512, 128);

    // t2 = h1 @ W3 -> fp32 [N,128]
    k_mgemm<0><<<MB128 * 1, blk, 0, stream>>>(H1p, W3T, nullptr, nullptr, t2, N, 128, 512);

    // h2 = leaky(Agg(t2) + b3) -> packed [N,128]
    k_gather<true><<<(N * 64 + 255) / 256, blk, 0, stream>>>(t2, rowptr, csr, dinv, b3, A3p, N);

    // out = leaky(h2 @ fc1_w^T + fc1_b) @ fc2_w^T + fc2_b  (fc2 fused, atomic partials)
    k_mgemm<2><<<MB128 * 2, blk, 0, stream>>>(A3p, F1p, fc1b, fc2w, out, N, 256, 128);
}